// Round 10
// baseline (486.855 us; speedup 1.0000x reference)
//
#include <hip/hip_runtime.h>
#include <hip/hip_bf16.h>

#define DIM 128
#define CAP 64
#define RSQRT_HD 0.17677669529663687f   // 1/sqrt(32)
#define CSR_BLOCKS 256

typedef float f32x4 __attribute__((ext_vector_type(4)));
typedef short bf16x8 __attribute__((ext_vector_type(8)));

__device__ __forceinline__ float bf2f(unsigned short u) {
    unsigned int x = ((unsigned int)u) << 16;
    union { unsigned int i; float f; } c; c.i = x; return c.f;
}
__device__ __forceinline__ unsigned short f2bf(float f) {
    __hip_bfloat16 h = __float2bfloat16(f);
    unsigned short u;
    __builtin_memcpy(&u, &h, 2);
    return u;
}
__device__ __forceinline__ void wave_lds_fence() {
    asm volatile("s_waitcnt lgkmcnt(0)" ::: "memory");
    __builtin_amdgcn_sched_barrier(0);
}

// ---------------- fp32 -> bf16 weight cast: 4 weights of 128x128, grid (8,4) ----------------
__global__ __launch_bounds__(256) void cast_w4(
    const float* __restrict__ a, const float* __restrict__ b,
    const float* __restrict__ c, const float* __restrict__ d,
    unsigned short* __restrict__ oa, unsigned short* __restrict__ ob,
    unsigned short* __restrict__ oc, unsigned short* __restrict__ od)
{
    int w = blockIdx.y;
    const float* s = (w == 0) ? a : (w == 1) ? b : (w == 2) ? c : d;
    unsigned short* o = (w == 0) ? oa : (w == 1) ? ob : (w == 2) ? oc : od;
    int i = blockIdx.x * 256 + threadIdx.x;   // 0..2047
    f32x4 v0 = ((const f32x4*)s)[2 * i];
    f32x4 v1 = ((const f32x4*)s)[2 * i + 1];
    bf16x8 ov;
    ov[0] = (short)f2bf(v0[0]); ov[1] = (short)f2bf(v0[1]);
    ov[2] = (short)f2bf(v0[2]); ov[3] = (short)f2bf(v0[3]);
    ov[4] = (short)f2bf(v1[0]); ov[5] = (short)f2bf(v1[1]);
    ov[6] = (short)f2bf(v1[2]); ov[7] = (short)f2bf(v1[3]);
    ((bf16x8*)o)[i] = ov;
}

// ---------------- single-kernel CSR build ----------------
// 256 blocks (1/CU, all co-resident) + device-scope spin barriers.
// bar[0..4]: per-phase arrival counters; bar[5]: dtype flag (nonzero => int32).
__device__ __forceinline__ void gridbar(int* cnt)
{
    __syncthreads();
    if (threadIdx.x == 0) {
        __threadfence();                               // release my stores
        atomicAdd(cnt, 1);
        while (__hip_atomic_load(cnt, __ATOMIC_RELAXED, __HIP_MEMORY_SCOPE_AGENT) < CSR_BLOCKS)
            __builtin_amdgcn_s_sleep(2);
        __threadfence();                               // acquire: invalidate L1
    }
    __syncthreads();
}

__global__ __launch_bounds__(256) void csr_build(
    const int* __restrict__ e32, const long long* __restrict__ e64,
    int* __restrict__ deg, int* __restrict__ tmp, int* __restrict__ rowptr,
    int* __restrict__ cursor, int* __restrict__ colidx, int* __restrict__ eidb,
    int* __restrict__ bsums, int* __restrict__ bar, int N, int E)
{
    int t = threadIdx.x, b = blockIdx.x;
    int gid = b * 256 + t;
    const int gsz = CSR_BLOCKS * 256;
    int nb = (N + 1023) >> 10;
    __shared__ int s[512];

    // phase A: zero deg (grid-stride); block 0 detects int64 vs int32
    for (int i = gid; i < N; i += gsz) deg[i] = 0;
    if (b == 0) {
        int lim = (2 * E < 4096) ? 2 * E : 4096;
        int nz = 0;
        for (int i = 2 * t + 1; i < lim; i += 512) nz |= (e32[i] != 0);
        if (nz) atomicOr(&bar[5], 1);   // any odd word nonzero => int32 payload
    }
    gridbar(&bar[0]);

    int is64 = (__hip_atomic_load(&bar[5], __ATOMIC_RELAXED, __HIP_MEMORY_SCOPE_AGENT) == 0);

    // phase B: histogram of destination rows
    for (int e = gid; e < E; e += gsz) {
        int r = is64 ? (int)e64[e] : e32[e];
        atomicAdd(&deg[r], 1);
    }
    gridbar(&bar[1]);

    // phase C: per-1024-chunk inclusive scan (blocks 0..nb-1)
    if (b < nb) {
        int base = b * 1024 + t * 4;
        int v0 = (base + 0 < N) ? deg[base + 0] : 0;
        int v1 = (base + 1 < N) ? deg[base + 1] : 0;
        int v2 = (base + 2 < N) ? deg[base + 2] : 0;
        int v3 = (base + 3 < N) ? deg[base + 3] : 0;
        int sum = v0 + v1 + v2 + v3;
        s[t] = sum;
        __syncthreads();
        for (int off = 1; off < 256; off <<= 1) {
            int x = (t >= off) ? s[t - off] : 0;
            __syncthreads();
            s[t] += x;
            __syncthreads();
        }
        int excl = s[t] - sum;
        if (base + 0 < N) tmp[base + 0] = excl + v0;
        if (base + 1 < N) tmp[base + 1] = excl + v0 + v1;
        if (base + 2 < N) tmp[base + 2] = excl + v0 + v1 + v2;
        if (base + 3 < N) tmp[base + 3] = excl + sum;
        if (t == 255) bsums[b] = s[255];
    }
    gridbar(&bar[2]);

    // phase D: exclusive scan of bsums (block 0; nb <= 512)
    if (b == 0) {
        s[t] = (t < nb) ? bsums[t] : 0;
        s[t + 256] = (t + 256 < nb) ? bsums[t + 256] : 0;
        __syncthreads();
        for (int off = 1; off < 512; off <<= 1) {
            int x0 = (t >= off) ? s[t - off] : 0;
            int i1 = t + 256;
            int x1 = (i1 >= off) ? s[i1 - off] : 0;
            __syncthreads();
            s[t] += x0;
            s[i1] += x1;
            __syncthreads();
        }
        if (t < nb) bsums[t] = (t == 0) ? 0 : s[t - 1];
        if (t + 256 < nb) bsums[t + 256] = s[t + 255];
    }
    gridbar(&bar[3]);

    // phase E: rowptr + cursor (cursor[i] = segment start = rowptr[i])
    for (int i = gid; i < N; i += gsz) {
        int rp1 = tmp[i] + bsums[i >> 10];
        rowptr[i + 1] = rp1;
        cursor[i] = rp1 - deg[i];
        if (i == 0) rowptr[0] = 0;
    }
    gridbar(&bar[4]);

    // phase F: scatter edges into CSR slots
    for (int e = gid; e < E; e += gsz) {
        int r = is64 ? (int)e64[e] : e32[e];
        int c = is64 ? (int)e64[e + E] : e32[e + E];
        int pos = atomicAdd(&cursor[r], 1);
        colidx[pos] = c;
        eidb[pos] = e;
    }
}

// ---------------- fused QKV MFMA GEMM: reads X once, computes Q,K,V ----------------
// 256 thr = 4 waves; wave owns 32 rows x 128 cols. X staged once in registers.
// C-writes staged through LDS so global stores are coalesced bf16x8 (16B/lane)
// instead of 64 scattered 2B stores per wave.
__global__ __launch_bounds__(256) void gemm_qkv_fused(const float* __restrict__ X,
    const unsigned short* __restrict__ Wq, const unsigned short* __restrict__ Wk,
    const unsigned short* __restrict__ Wv,
    const float* __restrict__ bq, const float* __restrict__ bk, const float* __restrict__ bv,
    unsigned short* __restrict__ Q, unsigned short* __restrict__ K, unsigned short* __restrict__ V,
    int M)
{
    __shared__ unsigned short cst[4][32 * 136];   // per-wave 32x128 tile, pad 136
    int lane = threadIdx.x & 63;
    int wave = threadIdx.x >> 6;
    int row0 = blockIdx.x * 128 + wave * 32;
    int r16 = lane & 15;
    int kg = lane >> 4;
    int koff = kg * 8;

    int ra0 = row0 + r16;       if (ra0 > M - 1) ra0 = M - 1;
    int ra1 = row0 + 16 + r16;  if (ra1 > M - 1) ra1 = M - 1;
    const float* pa0f = X + (size_t)ra0 * DIM + koff;
    const float* pa1f = X + (size_t)ra1 * DIM + koff;

    bf16x8 xa0[4], xa1[4];
#pragma unroll
    for (int kt = 0; kt < 4; ++kt) {
        int k0 = kt * 32;
        f32x4 lo0 = *(const f32x4*)(pa0f + k0), hi0 = *(const f32x4*)(pa0f + k0 + 4);
        f32x4 lo1 = *(const f32x4*)(pa1f + k0), hi1 = *(const f32x4*)(pa1f + k0 + 4);
#pragma unroll
        for (int j = 0; j < 4; ++j) {
            xa0[kt][j] = (short)f2bf(lo0[j]); xa0[kt][j + 4] = (short)f2bf(hi0[j]);
            xa1[kt][j] = (short)f2bf(lo1[j]); xa1[kt][j + 4] = (short)f2bf(hi1[j]);
        }
    }

    unsigned short* my = &cst[wave][0];
#pragma unroll
    for (int w = 0; w < 3; ++w) {
        const unsigned short* W = (w == 0) ? Wq : (w == 1) ? Wk : Wv;
        const float* bias        = (w == 0) ? bq : (w == 1) ? bk : bv;
        unsigned short* out      = (w == 0) ? Q  : (w == 1) ? K  : V;

        f32x4 acc[2][8] = {};
        const unsigned short* pw = W + r16 * DIM + koff;
#pragma unroll
        for (int kt = 0; kt < 4; ++kt) {
            int k0 = kt * 32;
            bf16x8 bw[8];
#pragma unroll
            for (int ct = 0; ct < 8; ++ct)
                bw[ct] = *(const bf16x8*)(pw + ct * 16 * DIM + k0);
#pragma unroll
            for (int ct = 0; ct < 8; ++ct) {
                acc[0][ct] = __builtin_amdgcn_mfma_f32_16x16x32_bf16(xa0[kt], bw[ct], acc[0][ct], 0, 0, 0);
                acc[1][ct] = __builtin_amdgcn_mfma_f32_16x16x32_bf16(xa1[kt], bw[ct], acc[1][ct], 0, 0, 0);
            }
        }

        float biasv[8];
#pragma unroll
        for (int ct = 0; ct < 8; ++ct) biasv[ct] = bias[ct * 16 + r16];

        // C -> LDS (row-major, lane-scattered 2B) ...
#pragma unroll
        for (int rt = 0; rt < 2; ++rt)
#pragma unroll
            for (int ct = 0; ct < 8; ++ct)
#pragma unroll
                for (int j = 0; j < 4; ++j)
                    my[(rt * 16 + kg * 4 + j) * 136 + ct * 16 + r16] =
                        f2bf(acc[rt][ct][j] + biasv[ct]);
        wave_lds_fence();
        // ... LDS -> global, coalesced 16B/lane (4 rows x 256B per pass)
#pragma unroll
        for (int pass = 0; pass < 8; ++pass) {
            int rr = pass * 4 + (lane >> 4);
            bf16x8 v = *(const bf16x8*)(my + rr * 136 + (lane & 15) * 8);
            int gr = row0 + rr;
            if (gr < M) *(bf16x8*)(out + (size_t)gr * DIM + (lane & 15) * 8) = v;
        }
        wave_lds_fence();   // cst reused by next matrix
    }
}

// ---------------- final GEMM: out = A@Wo^T + bo + res (fp32 out) ----------------
__global__ __launch_bounds__(256) void gemm_final(const unsigned short* __restrict__ A,
    const unsigned short* __restrict__ W, const float* __restrict__ bias,
    const float* __restrict__ res, float* __restrict__ out, int M)
{
    int lane = threadIdx.x & 63;
    int wave = threadIdx.x >> 6;
    int row0 = blockIdx.x * 128 + wave * 32;
    int r16 = lane & 15;
    int kg = lane >> 4;
    int koff = kg * 8;

    f32x4 acc[2][8] = {};
    int ra0 = row0 + r16;       if (ra0 > M - 1) ra0 = M - 1;
    int ra1 = row0 + 16 + r16;  if (ra1 > M - 1) ra1 = M - 1;
    const unsigned short* pa0 = A + (size_t)ra0 * DIM + koff;
    const unsigned short* pa1 = A + (size_t)ra1 * DIM + koff;
    const unsigned short* pw = W + r16 * DIM + koff;

#pragma unroll
    for (int k0 = 0; k0 < 128; k0 += 32) {
        bf16x8 a0 = *(const bf16x8*)(pa0 + k0);
        bf16x8 a1 = *(const bf16x8*)(pa1 + k0);
        bf16x8 bw[8];
#pragma unroll
        for (int ct = 0; ct < 8; ++ct)
            bw[ct] = *(const bf16x8*)(pw + ct * 16 * DIM + k0);
#pragma unroll
        for (int ct = 0; ct < 8; ++ct) {
            acc[0][ct] = __builtin_amdgcn_mfma_f32_16x16x32_bf16(a0, bw[ct], acc[0][ct], 0, 0, 0);
            acc[1][ct] = __builtin_amdgcn_mfma_f32_16x16x32_bf16(a1, bw[ct], acc[1][ct], 0, 0, 0);
        }
    }

    float biasv[8];
#pragma unroll
    for (int ct = 0; ct < 8; ++ct) biasv[ct] = bias[ct * 16 + r16];
#pragma unroll
    for (int rt = 0; rt < 2; ++rt) {
        int rbase = row0 + rt * 16 + kg * 4;
#pragma unroll
        for (int ct = 0; ct < 8; ++ct) {
            int c = ct * 16 + r16;
#pragma unroll
            for (int j = 0; j < 4; ++j) {
                int r = rbase + j;
                if (r < M)
                    out[(size_t)r * DIM + c] = acc[rt][ct][j] + biasv[ct] + res[(size_t)r * DIM + c];
            }
        }
    }
}

// ---------------- per-destination-node attention, one WAVE per node ----------------
// 256 thr = 4 waves = 4 nodes/block. lane l owns dims (2l, 2l+1); head h = l>>4.
// Wave-synchronous LDS (lgkmcnt fences, rule #18). Score/PV loops are 4-wide
// chunked: 4 independent row gathers in flight (validated round 7: 139->94us).
__global__ __launch_bounds__(256) void attn_kernel(const unsigned short* __restrict__ Q,
    const unsigned short* __restrict__ K, const unsigned short* __restrict__ V,
    const int* __restrict__ rowptr, const int* __restrict__ colidx,
    const int* __restrict__ eidb, unsigned short* __restrict__ attended,
    float* __restrict__ avg_out, int N)
{
    __shared__ float sc_s[4][CAP * 5];
    __shared__ int scol_s[4][CAP];
    __shared__ int sei_s[4][CAP];

    int wave = threadIdx.x >> 6;
    int l = threadIdx.x & 63;
    int n = blockIdx.x * 4 + wave;
    bool active = n < N;
    int h = l >> 4;       // head
    int hl = l & 15;      // lane within head group
    float* sc = sc_s[wave];
    int* scol = scol_s[wave];
    int* sei = sei_s[wave];

    int s0 = active ? rowptr[n] : 0;
    int deg = active ? (rowptr[n + 1] - s0) : 0;

    float q0 = 0.f, q1 = 0.f;
    if (active) {
        ushort2 qq = *(const ushort2*)(Q + (size_t)n * DIM + 2 * l);
        q0 = bf2f(qq.x); q1 = bf2f(qq.y);
    }

    if (deg <= CAP) {
        for (int e = l; e < deg; e += 64) { scol[e] = colidx[s0 + e]; sei[e] = eidb[s0 + e]; }
        wave_lds_fence();
        int e = 0;
        for (; e + 4 <= deg; e += 4) {
            int c0 = scol[e], c1 = scol[e + 1], c2 = scol[e + 2], c3 = scol[e + 3];
            ushort2 k0v = *(const ushort2*)(K + (size_t)c0 * DIM + 2 * l);
            ushort2 k1v = *(const ushort2*)(K + (size_t)c1 * DIM + 2 * l);
            ushort2 k2v = *(const ushort2*)(K + (size_t)c2 * DIM + 2 * l);
            ushort2 k3v = *(const ushort2*)(K + (size_t)c3 * DIM + 2 * l);
            float p0 = q0 * bf2f(k0v.x) + q1 * bf2f(k0v.y);
            float p1 = q0 * bf2f(k1v.x) + q1 * bf2f(k1v.y);
            float p2 = q0 * bf2f(k2v.x) + q1 * bf2f(k2v.y);
            float p3 = q0 * bf2f(k3v.x) + q1 * bf2f(k3v.y);
#pragma unroll
            for (int off = 8; off; off >>= 1) {
                p0 += __shfl_xor(p0, off); p1 += __shfl_xor(p1, off);
                p2 += __shfl_xor(p2, off); p3 += __shfl_xor(p3, off);
            }
            if (hl == 0) {
                sc[(e + 0) * 5 + h] = p0 * RSQRT_HD;
                sc[(e + 1) * 5 + h] = p1 * RSQRT_HD;
                sc[(e + 2) * 5 + h] = p2 * RSQRT_HD;
                sc[(e + 3) * 5 + h] = p3 * RSQRT_HD;
            }
        }
        for (; e < deg; ++e) {
            int c = scol[e];
            ushort2 kk = *(const ushort2*)(K + (size_t)c * DIM + 2 * l);
            float p = q0 * bf2f(kk.x) + q1 * bf2f(kk.y);
#pragma unroll
            for (int off = 8; off; off >>= 1) p += __shfl_xor(p, off);
            if (hl == 0) sc[e * 5 + h] = p * RSQRT_HD;
        }
        wave_lds_fence();
        float m = -INFINITY;
        for (int e2 = hl; e2 < deg; e2 += 16) m = fmaxf(m, sc[e2 * 5 + h]);
#pragma unroll
        for (int off = 8; off; off >>= 1) m = fmaxf(m, __shfl_xor(m, off));
        float ssum = 0.f;
        for (int e2 = hl; e2 < deg; e2 += 16) ssum += __expf(sc[e2 * 5 + h] - m);
#pragma unroll
        for (int off = 8; off; off >>= 1) ssum += __shfl_xor(ssum, off);
        float inv = 1.f / (ssum + 1e-16f);
        for (int e2 = hl; e2 < deg; e2 += 16) sc[e2 * 5 + h] = __expf(sc[e2 * 5 + h] - m) * inv;
        wave_lds_fence();
        for (int e2 = l; e2 < deg; e2 += 64)
            avg_out[sei[e2]] = 0.25f * (sc[e2 * 5] + sc[e2 * 5 + 1] + sc[e2 * 5 + 2] + sc[e2 * 5 + 3]);
        float a0 = 0.f, a1 = 0.f;
        int e3 = 0;
        for (; e3 + 4 <= deg; e3 += 4) {
            int c0 = scol[e3], c1 = scol[e3 + 1], c2 = scol[e3 + 2], c3 = scol[e3 + 3];
            float w0 = sc[(e3 + 0) * 5 + h];
            float w1 = sc[(e3 + 1) * 5 + h];
            float w2 = sc[(e3 + 2) * 5 + h];
            float w3 = sc[(e3 + 3) * 5 + h];
            ushort2 v0 = *(const ushort2*)(V + (size_t)c0 * DIM + 2 * l);
            ushort2 v1 = *(const ushort2*)(V + (size_t)c1 * DIM + 2 * l);
            ushort2 v2 = *(const ushort2*)(V + (size_t)c2 * DIM + 2 * l);
            ushort2 v3 = *(const ushort2*)(V + (size_t)c3 * DIM + 2 * l);
            a0 += w0 * bf2f(v0.x); a1 += w0 * bf2f(v0.y);
            a0 += w1 * bf2f(v1.x); a1 += w1 * bf2f(v1.y);
            a0 += w2 * bf2f(v2.x); a1 += w2 * bf2f(v2.y);
            a0 += w3 * bf2f(v3.x); a1 += w3 * bf2f(v3.y);
        }
        for (; e3 < deg; ++e3) {
            float a = sc[e3 * 5 + h];
            ushort2 vv = *(const ushort2*)(V + (size_t)scol[e3] * DIM + 2 * l);
            a0 += a * bf2f(vv.x);
            a1 += a * bf2f(vv.y);
        }
        if (active) {
            ushort2 o; o.x = f2bf(a0); o.y = f2bf(a1);
            *(ushort2*)(attended + (size_t)n * DIM + 2 * l) = o;
        }
    } else {
        // streaming two-pass fallback (deg > CAP; correct for any degree)
        float m = -INFINITY, ssum = 0.f;
        for (int e = 0; e < deg; ++e) {
            int c = colidx[s0 + e];
            ushort2 kk = *(const ushort2*)(K + (size_t)c * DIM + 2 * l);
            float p = q0 * bf2f(kk.x) + q1 * bf2f(kk.y);
#pragma unroll
            for (int off = 8; off; off >>= 1) p += __shfl_xor(p, off);
            p *= RSQRT_HD;
            float mn = fmaxf(m, p);
            ssum = ssum * __expf(m - mn) + __expf(p - mn);
            m = mn;
        }
        float inv = 1.f / (ssum + 1e-16f);
        float a0 = 0.f, a1 = 0.f;
        for (int e = 0; e < deg; ++e) {
            int c = colidx[s0 + e];
            ushort2 kk = *(const ushort2*)(K + (size_t)c * DIM + 2 * l);
            float p = q0 * bf2f(kk.x) + q1 * bf2f(kk.y);
#pragma unroll
            for (int off = 8; off; off >>= 1) p += __shfl_xor(p, off);
            float a = __expf(p * RSQRT_HD - m) * inv;
            float asum = a + __shfl_xor(a, 16);
            asum += __shfl_xor(asum, 32);
            if (l == 0) avg_out[eidb[s0 + e]] = 0.25f * asum;
            ushort2 vv = *(const ushort2*)(V + (size_t)c * DIM + 2 * l);
            a0 += a * bf2f(vv.x);
            a1 += a * bf2f(vv.y);
        }
        if (active) {
            ushort2 o; o.x = f2bf(a0); o.y = f2bf(a1);
            *(ushort2*)(attended + (size_t)n * DIM + 2 * l) = o;
        }
    }
}

extern "C" void kernel_launch(void* const* d_in, const int* in_sizes, int n_in,
                              void* d_out, int out_size, void* d_ws, size_t ws_size,
                              hipStream_t stream)
{
    const float* x  = (const float*)d_in[0];
    const int* e32  = (const int*)d_in[1];
    const long long* e64 = (const long long*)d_in[1];
    const float* Wq = (const float*)d_in[2];
    const float* bq = (const float*)d_in[3];
    const float* Wk = (const float*)d_in[4];
    const float* bk = (const float*)d_in[5];
    const float* Wv = (const float*)d_in[6];
    const float* bv = (const float*)d_in[7];
    const float* Wo = (const float*)d_in[8];
    const float* bo = (const float*)d_in[9];

    int N = in_sizes[0] / DIM;
    int E = in_sizes[1] / 2;

    float* out = (float*)d_out;
    float* avg_out = out + (size_t)N * DIM;

    char* w = (char*)d_ws;
    auto carve = [&](size_t bytes) -> void* {
        void* p = (void*)w;
        w += (bytes + 255) & ~(size_t)255;
        return p;
    };
    unsigned short* Qb = (unsigned short*)carve((size_t)N * DIM * 2);  // reused as `attended`
    unsigned short* Kb = (unsigned short*)carve((size_t)N * DIM * 2);
    unsigned short* Vb = (unsigned short*)carve((size_t)N * DIM * 2);
    unsigned short* Wqb = (unsigned short*)carve(DIM * DIM * 2);
    unsigned short* Wkb = (unsigned short*)carve(DIM * DIM * 2);
    unsigned short* Wvb = (unsigned short*)carve(DIM * DIM * 2);
    unsigned short* Wob = (unsigned short*)carve(DIM * DIM * 2);
    int* deg    = (int*)carve((size_t)N * 4);
    int* tmp    = (int*)carve((size_t)N * 4);
    int* rowptr = (int*)carve(((size_t)N + 1) * 4);
    int* cursor = (int*)carve((size_t)N * 4);
    int* bsums  = (int*)carve(512 * 4);
    int* bar    = (int*)carve(256);
    int* colidx = (int*)carve((size_t)E * 4);
    int* eidb   = (int*)carve((size_t)E * 4);

    hipMemsetAsync(bar, 0, 256, stream);   // barrier counters + dtype flag

    cast_w4<<<dim3(8, 4), 256, 0, stream>>>(Wq, Wk, Wv, Wo, Wqb, Wkb, Wvb, Wob);

    csr_build<<<CSR_BLOCKS, 256, 0, stream>>>(e32, e64, deg, tmp, rowptr, cursor,
                                              colidx, eidb, bsums, bar, N, E);

    int gx = (N + 127) / 128;
    gemm_qkv_fused<<<gx, 256, 0, stream>>>(x, Wqb, Wkb, Wvb, bq, bk, bv, Qb, Kb, Vb, N);

    attn_kernel<<<(N + 3) / 4, 256, 0, stream>>>(Qb, Kb, Vb, rowptr, colidx, eidb,
                                                 Qb /*attended aliases Q*/, avg_out, N);

    gemm_final<<<gx, 256, 0, stream>>>(Qb, Wob, bo, x, out, N);
}

// Round 12
// 386.834 us; speedup vs baseline: 1.2586x; 1.2586x over previous
//
#include <hip/hip_runtime.h>
#include <hip/hip_bf16.h>

#define DIM 128
#define CAP 64
#define RSQRT_HD 0.17677669529663687f   // 1/sqrt(32)

typedef float f32x4 __attribute__((ext_vector_type(4)));
typedef short bf16x8 __attribute__((ext_vector_type(8)));

__device__ __forceinline__ float bf2f(unsigned short u) {
    unsigned int x = ((unsigned int)u) << 16;
    union { unsigned int i; float f; } c; c.i = x; return c.f;
}
__device__ __forceinline__ unsigned short f2bf(float f) {
    __hip_bfloat16 h = __float2bfloat16(f);
    unsigned short u;
    __builtin_memcpy(&u, &h, 2);
    return u;
}
__device__ __forceinline__ void wave_lds_fence() {
    asm volatile("s_waitcnt lgkmcnt(0)" ::: "memory");
    __builtin_amdgcn_sched_barrier(0);
}

// ---------------- fp32 -> bf16 weight cast: 4 weights of 128x128, grid (8,4) ----------------
__global__ __launch_bounds__(256) void cast_w4(
    const float* __restrict__ a, const float* __restrict__ b,
    const float* __restrict__ c, const float* __restrict__ d,
    unsigned short* __restrict__ oa, unsigned short* __restrict__ ob,
    unsigned short* __restrict__ oc, unsigned short* __restrict__ od)
{
    int w = blockIdx.y;
    const float* s = (w == 0) ? a : (w == 1) ? b : (w == 2) ? c : d;
    unsigned short* o = (w == 0) ? oa : (w == 1) ? ob : (w == 2) ? oc : od;
    int i = blockIdx.x * 256 + threadIdx.x;   // 0..2047
    f32x4 v0 = ((const f32x4*)s)[2 * i];
    f32x4 v1 = ((const f32x4*)s)[2 * i + 1];
    bf16x8 ov;
    ov[0] = (short)f2bf(v0[0]); ov[1] = (short)f2bf(v0[1]);
    ov[2] = (short)f2bf(v0[2]); ov[3] = (short)f2bf(v0[3]);
    ov[4] = (short)f2bf(v1[0]); ov[5] = (short)f2bf(v1[1]);
    ov[6] = (short)f2bf(v1[2]); ov[7] = (short)f2bf(v1[3]);
    ((bf16x8*)o)[i] = ov;
}

// ---------------- edge_index dtype detection (int64 vs int32) ----------------
__global__ void detect64(const int* __restrict__ e, int* __restrict__ flag, int E2)
{
    __shared__ int nz;
    int t = threadIdx.x;
    if (t == 0) nz = 0;
    __syncthreads();
    int lim = (E2 < 4096) ? E2 : 4096;
    int mynz = 0;
    for (int i = 2 * t + 1; i < lim; i += 512) mynz |= (e[i] != 0);
    if (mynz) atomicOr(&nz, 1);
    __syncthreads();
    if (t == 0) *flag = nz ? 0 : 1;    // all odd words zero => int64 data
}

__device__ __forceinline__ int load_idx(const int* p32, const long long* p64, int is64, int i)
{
    return is64 ? (int)p64[i] : p32[i];
}

// ---------------- CSR build (split kernels: max TLP for the atomic phases) ----------------
__global__ void hist_kernel(const int* __restrict__ row32, const long long* __restrict__ row64,
                            const int* __restrict__ flag, int* __restrict__ deg, int E)
{
    int e = blockIdx.x * blockDim.x + threadIdx.x;
    if (e < E) atomicAdd(&deg[load_idx(row32, row64, *flag, e)], 1);
}

__global__ __launch_bounds__(256) void scan1(const int* __restrict__ in, int* __restrict__ incl,
                                             int* __restrict__ bsums, int n)
{
    __shared__ int s[256];
    int t = threadIdx.x;
    int base = blockIdx.x * 1024 + t * 4;
    int v0 = (base + 0 < n) ? in[base + 0] : 0;
    int v1 = (base + 1 < n) ? in[base + 1] : 0;
    int v2 = (base + 2 < n) ? in[base + 2] : 0;
    int v3 = (base + 3 < n) ? in[base + 3] : 0;
    int sum = v0 + v1 + v2 + v3;
    s[t] = sum;
    __syncthreads();
    for (int off = 1; off < 256; off <<= 1) {
        int x = (t >= off) ? s[t - off] : 0;
        __syncthreads();
        s[t] += x;
        __syncthreads();
    }
    int excl = s[t] - sum;
    if (base + 0 < n) incl[base + 0] = excl + v0;
    if (base + 1 < n) incl[base + 1] = excl + v0 + v1;
    if (base + 2 < n) incl[base + 2] = excl + v0 + v1 + v2;
    if (base + 3 < n) incl[base + 3] = excl + sum;
    if (t == 255) bsums[blockIdx.x] = s[255];
}

// parallel exclusive scan of bsums (nb <= 512), one block of 256
__global__ __launch_bounds__(256) void scan2(int* bsums, int nb)
{
    __shared__ int s[512];
    int t = threadIdx.x;
    s[t] = (t < nb) ? bsums[t] : 0;
    s[t + 256] = (t + 256 < nb) ? bsums[t + 256] : 0;
    __syncthreads();
    for (int off = 1; off < 512; off <<= 1) {
        int x0 = (t >= off) ? s[t - off] : 0;
        int i1 = t + 256;
        int x1 = (i1 >= off) ? s[i1 - off] : 0;
        __syncthreads();
        s[t] += x0;
        s[i1] += x1;
        __syncthreads();
    }
    // exclusive from inclusive
    if (t < nb) bsums[t] = (t == 0) ? 0 : s[t - 1];
    if (t + 256 < nb) bsums[t + 256] = s[t + 255];
}

// rowptr + cursor in one pass (cursor[i] = segment start; drops the d2d memcpy)
__global__ void scan3c(const int* __restrict__ incl, const int* __restrict__ bofs,
                       const int* __restrict__ deg, int* __restrict__ rowptr,
                       int* __restrict__ cursor, int n)
{
    int i = blockIdx.x * 256 + threadIdx.x;
    if (i == 0) rowptr[0] = 0;
    if (i < n) {
        int rp1 = incl[i] + bofs[i >> 10];
        rowptr[i + 1] = rp1;
        cursor[i] = rp1 - deg[i];
    }
}

// paired 8B store {col, edge_id}: half the dirtied cachelines vs two 4B arrays
__global__ void scatter_kernel(const int* __restrict__ e32, const long long* __restrict__ e64,
                               const int* __restrict__ flag,
                               int* __restrict__ cursor, int2* __restrict__ colEid, int E)
{
    int e = blockIdx.x * blockDim.x + threadIdx.x;
    if (e < E) {
        int is64 = *flag;
        int r = load_idx(e32, e64, is64, e);
        int c = load_idx(e32 + E, e64 + E, is64, e);
        int pos = atomicAdd(&cursor[r], 1);
        colEid[pos] = make_int2(c, e);
    }
}

// ---------------- fused QKV MFMA GEMM: reads X once, computes Q,K,V ----------------
// 256 thr = 4 waves; wave owns 32 rows x 128 cols. X staged once in registers.
// C-writes staged through LDS -> coalesced bf16x8 global stores.
__global__ __launch_bounds__(256) void gemm_qkv_fused(const float* __restrict__ X,
    const unsigned short* __restrict__ Wq, const unsigned short* __restrict__ Wk,
    const unsigned short* __restrict__ Wv,
    const float* __restrict__ bq, const float* __restrict__ bk, const float* __restrict__ bv,
    unsigned short* __restrict__ Q, unsigned short* __restrict__ K, unsigned short* __restrict__ V,
    int M)
{
    __shared__ unsigned short cst[4][32 * 136];   // per-wave 32x128 tile, pad 136
    int lane = threadIdx.x & 63;
    int wave = threadIdx.x >> 6;
    int row0 = blockIdx.x * 128 + wave * 32;
    int r16 = lane & 15;
    int kg = lane >> 4;
    int koff = kg * 8;

    int ra0 = row0 + r16;       if (ra0 > M - 1) ra0 = M - 1;
    int ra1 = row0 + 16 + r16;  if (ra1 > M - 1) ra1 = M - 1;
    const float* pa0f = X + (size_t)ra0 * DIM + koff;
    const float* pa1f = X + (size_t)ra1 * DIM + koff;

    bf16x8 xa0[4], xa1[4];
#pragma unroll
    for (int kt = 0; kt < 4; ++kt) {
        int k0 = kt * 32;
        f32x4 lo0 = *(const f32x4*)(pa0f + k0), hi0 = *(const f32x4*)(pa0f + k0 + 4);
        f32x4 lo1 = *(const f32x4*)(pa1f + k0), hi1 = *(const f32x4*)(pa1f + k0 + 4);
#pragma unroll
        for (int j = 0; j < 4; ++j) {
            xa0[kt][j] = (short)f2bf(lo0[j]); xa0[kt][j + 4] = (short)f2bf(hi0[j]);
            xa1[kt][j] = (short)f2bf(lo1[j]); xa1[kt][j + 4] = (short)f2bf(hi1[j]);
        }
    }

    unsigned short* my = &cst[wave][0];
#pragma unroll
    for (int w = 0; w < 3; ++w) {
        const unsigned short* W = (w == 0) ? Wq : (w == 1) ? Wk : Wv;
        const float* bias        = (w == 0) ? bq : (w == 1) ? bk : bv;
        unsigned short* out      = (w == 0) ? Q  : (w == 1) ? K  : V;

        f32x4 acc[2][8] = {};
        const unsigned short* pw = W + r16 * DIM + koff;
#pragma unroll
        for (int kt = 0; kt < 4; ++kt) {
            int k0 = kt * 32;
            bf16x8 bw[8];
#pragma unroll
            for (int ct = 0; ct < 8; ++ct)
                bw[ct] = *(const bf16x8*)(pw + ct * 16 * DIM + k0);
#pragma unroll
            for (int ct = 0; ct < 8; ++ct) {
                acc[0][ct] = __builtin_amdgcn_mfma_f32_16x16x32_bf16(xa0[kt], bw[ct], acc[0][ct], 0, 0, 0);
                acc[1][ct] = __builtin_amdgcn_mfma_f32_16x16x32_bf16(xa1[kt], bw[ct], acc[1][ct], 0, 0, 0);
            }
        }

        float biasv[8];
#pragma unroll
        for (int ct = 0; ct < 8; ++ct) biasv[ct] = bias[ct * 16 + r16];

#pragma unroll
        for (int rt = 0; rt < 2; ++rt)
#pragma unroll
            for (int ct = 0; ct < 8; ++ct)
#pragma unroll
                for (int j = 0; j < 4; ++j)
                    my[(rt * 16 + kg * 4 + j) * 136 + ct * 16 + r16] =
                        f2bf(acc[rt][ct][j] + biasv[ct]);
        wave_lds_fence();
#pragma unroll
        for (int pass = 0; pass < 8; ++pass) {
            int rr = pass * 4 + (lane >> 4);
            bf16x8 v = *(const bf16x8*)(my + rr * 136 + (lane & 15) * 8);
            int gr = row0 + rr;
            if (gr < M) *(bf16x8*)(out + (size_t)gr * DIM + (lane & 15) * 8) = v;
        }
        wave_lds_fence();   // cst reused by next matrix
    }
}

// ---------------- final GEMM: out = A@Wo^T + bo + res (fp32 out) ----------------
__global__ __launch_bounds__(256) void gemm_final(const unsigned short* __restrict__ A,
    const unsigned short* __restrict__ W, const float* __restrict__ bias,
    const float* __restrict__ res, float* __restrict__ out, int M)
{
    int lane = threadIdx.x & 63;
    int wave = threadIdx.x >> 6;
    int row0 = blockIdx.x * 128 + wave * 32;
    int r16 = lane & 15;
    int kg = lane >> 4;
    int koff = kg * 8;

    f32x4 acc[2][8] = {};
    int ra0 = row0 + r16;       if (ra0 > M - 1) ra0 = M - 1;
    int ra1 = row0 + 16 + r16;  if (ra1 > M - 1) ra1 = M - 1;
    const unsigned short* pa0 = A + (size_t)ra0 * DIM + koff;
    const unsigned short* pa1 = A + (size_t)ra1 * DIM + koff;
    const unsigned short* pw = W + r16 * DIM + koff;

#pragma unroll
    for (int k0 = 0; k0 < 128; k0 += 32) {
        bf16x8 a0 = *(const bf16x8*)(pa0 + k0);
        bf16x8 a1 = *(const bf16x8*)(pa1 + k0);
        bf16x8 bw[8];
#pragma unroll
        for (int ct = 0; ct < 8; ++ct)
            bw[ct] = *(const bf16x8*)(pw + ct * 16 * DIM + k0);
#pragma unroll
        for (int ct = 0; ct < 8; ++ct) {
            acc[0][ct] = __builtin_amdgcn_mfma_f32_16x16x32_bf16(a0, bw[ct], acc[0][ct], 0, 0, 0);
            acc[1][ct] = __builtin_amdgcn_mfma_f32_16x16x32_bf16(a1, bw[ct], acc[1][ct], 0, 0, 0);
        }
    }

    float biasv[8];
#pragma unroll
    for (int ct = 0; ct < 8; ++ct) biasv[ct] = bias[ct * 16 + r16];
#pragma unroll
    for (int rt = 0; rt < 2; ++rt) {
        int rbase = row0 + rt * 16 + kg * 4;
#pragma unroll
        for (int ct = 0; ct < 8; ++ct) {
            int c = ct * 16 + r16;
#pragma unroll
            for (int j = 0; j < 4; ++j) {
                int r = rbase + j;
                if (r < M)
                    out[(size_t)r * DIM + c] = acc[rt][ct][j] + biasv[ct] + res[(size_t)r * DIM + c];
            }
        }
    }
}

// ---------------- per-destination-node attention, one WAVE per node ----------------
// 256 thr = 4 waves = 4 nodes/block. lane l owns dims (2l, 2l+1); head h = l>>4.
// Wave-synchronous LDS (lgkmcnt fences). 4-wide chunked gathers (validated r7).
__global__ __launch_bounds__(256) void attn_kernel(const unsigned short* __restrict__ Q,
    const unsigned short* __restrict__ K, const unsigned short* __restrict__ V,
    const int* __restrict__ rowptr, const int2* __restrict__ colEid,
    unsigned short* __restrict__ attended, float* __restrict__ avg_out, int N)
{
    __shared__ float sc_s[4][CAP * 5];
    __shared__ int2 sce_s[4][CAP];

    int wave = threadIdx.x >> 6;
    int l = threadIdx.x & 63;
    int n = blockIdx.x * 4 + wave;
    bool active = n < N;
    int h = l >> 4;       // head
    int hl = l & 15;      // lane within head group
    float* sc = sc_s[wave];
    int2* sce = sce_s[wave];

    int s0 = active ? rowptr[n] : 0;
    int deg = active ? (rowptr[n + 1] - s0) : 0;

    float q0 = 0.f, q1 = 0.f;
    if (active) {
        ushort2 qq = *(const ushort2*)(Q + (size_t)n * DIM + 2 * l);
        q0 = bf2f(qq.x); q1 = bf2f(qq.y);
    }

    if (deg <= CAP) {
        for (int e = l; e < deg; e += 64) sce[e] = colEid[s0 + e];
        wave_lds_fence();
        int e = 0;
        for (; e + 4 <= deg; e += 4) {
            int c0 = sce[e].x, c1 = sce[e + 1].x, c2 = sce[e + 2].x, c3 = sce[e + 3].x;
            ushort2 k0v = *(const ushort2*)(K + (size_t)c0 * DIM + 2 * l);
            ushort2 k1v = *(const ushort2*)(K + (size_t)c1 * DIM + 2 * l);
            ushort2 k2v = *(const ushort2*)(K + (size_t)c2 * DIM + 2 * l);
            ushort2 k3v = *(const ushort2*)(K + (size_t)c3 * DIM + 2 * l);
            float p0 = q0 * bf2f(k0v.x) + q1 * bf2f(k0v.y);
            float p1 = q0 * bf2f(k1v.x) + q1 * bf2f(k1v.y);
            float p2 = q0 * bf2f(k2v.x) + q1 * bf2f(k2v.y);
            float p3 = q0 * bf2f(k3v.x) + q1 * bf2f(k3v.y);
#pragma unroll
            for (int off = 8; off; off >>= 1) {
                p0 += __shfl_xor(p0, off); p1 += __shfl_xor(p1, off);
                p2 += __shfl_xor(p2, off); p3 += __shfl_xor(p3, off);
            }
            if (hl == 0) {
                sc[(e + 0) * 5 + h] = p0 * RSQRT_HD;
                sc[(e + 1) * 5 + h] = p1 * RSQRT_HD;
                sc[(e + 2) * 5 + h] = p2 * RSQRT_HD;
                sc[(e + 3) * 5 + h] = p3 * RSQRT_HD;
            }
        }
        for (; e < deg; ++e) {
            int c = sce[e].x;
            ushort2 kk = *(const ushort2*)(K + (size_t)c * DIM + 2 * l);
            float p = q0 * bf2f(kk.x) + q1 * bf2f(kk.y);
#pragma unroll
            for (int off = 8; off; off >>= 1) p += __shfl_xor(p, off);
            if (hl == 0) sc[e * 5 + h] = p * RSQRT_HD;
        }
        wave_lds_fence();
        float m = -INFINITY;
        for (int e2 = hl; e2 < deg; e2 += 16) m = fmaxf(m, sc[e2 * 5 + h]);
#pragma unroll
        for (int off = 8; off; off >>= 1) m = fmaxf(m, __shfl_xor(m, off));
        float ssum = 0.f;
        for (int e2 = hl; e2 < deg; e2 += 16) ssum += __expf(sc[e2 * 5 + h] - m);
#pragma unroll
        for (int off = 8; off; off >>= 1) ssum += __shfl_xor(ssum, off);
        float inv = 1.f / (ssum + 1e-16f);
        for (int e2 = hl; e2 < deg; e2 += 16) sc[e2 * 5 + h] = __expf(sc[e2 * 5 + h] - m) * inv;
        wave_lds_fence();
        for (int e2 = l; e2 < deg; e2 += 64)
            avg_out[sce[e2].y] = 0.25f * (sc[e2 * 5] + sc[e2 * 5 + 1] + sc[e2 * 5 + 2] + sc[e2 * 5 + 3]);
        float a0 = 0.f, a1 = 0.f;
        int e3 = 0;
        for (; e3 + 4 <= deg; e3 += 4) {
            int c0 = sce[e3].x, c1 = sce[e3 + 1].x, c2 = sce[e3 + 2].x, c3 = sce[e3 + 3].x;
            float w0 = sc[(e3 + 0) * 5 + h];
            float w1 = sc[(e3 + 1) * 5 + h];
            float w2 = sc[(e3 + 2) * 5 + h];
            float w3 = sc[(e3 + 3) * 5 + h];
            ushort2 v0 = *(const ushort2*)(V + (size_t)c0 * DIM + 2 * l);
            ushort2 v1 = *(const ushort2*)(V + (size_t)c1 * DIM + 2 * l);
            ushort2 v2 = *(const ushort2*)(V + (size_t)c2 * DIM + 2 * l);
            ushort2 v3 = *(const ushort2*)(V + (size_t)c3 * DIM + 2 * l);
            a0 += w0 * bf2f(v0.x); a1 += w0 * bf2f(v0.y);
            a0 += w1 * bf2f(v1.x); a1 += w1 * bf2f(v1.y);
            a0 += w2 * bf2f(v2.x); a1 += w2 * bf2f(v2.y);
            a0 += w3 * bf2f(v3.x); a1 += w3 * bf2f(v3.y);
        }
        for (; e3 < deg; ++e3) {
            float a = sc[e3 * 5 + h];
            ushort2 vv = *(const ushort2*)(V + (size_t)sce[e3].x * DIM + 2 * l);
            a0 += a * bf2f(vv.x);
            a1 += a * bf2f(vv.y);
        }
        if (active) {
            ushort2 o; o.x = f2bf(a0); o.y = f2bf(a1);
            *(ushort2*)(attended + (size_t)n * DIM + 2 * l) = o;
        }
    } else {
        // streaming two-pass fallback (deg > CAP; correct for any degree)
        float m = -INFINITY, ssum = 0.f;
        for (int e = 0; e < deg; ++e) {
            int c = colEid[s0 + e].x;
            ushort2 kk = *(const ushort2*)(K + (size_t)c * DIM + 2 * l);
            float p = q0 * bf2f(kk.x) + q1 * bf2f(kk.y);
#pragma unroll
            for (int off = 8; off; off >>= 1) p += __shfl_xor(p, off);
            p *= RSQRT_HD;
            float mn = fmaxf(m, p);
            ssum = ssum * __expf(m - mn) + __expf(p - mn);
            m = mn;
        }
        float inv = 1.f / (ssum + 1e-16f);
        float a0 = 0.f, a1 = 0.f;
        for (int e = 0; e < deg; ++e) {
            int2 ce = colEid[s0 + e];
            ushort2 kk = *(const ushort2*)(K + (size_t)ce.x * DIM + 2 * l);
            float p = q0 * bf2f(kk.x) + q1 * bf2f(kk.y);
#pragma unroll
            for (int off = 8; off; off >>= 1) p += __shfl_xor(p, off);
            float a = __expf(p * RSQRT_HD - m) * inv;
            float asum = a + __shfl_xor(a, 16);
            asum += __shfl_xor(asum, 32);
            if (l == 0) avg_out[ce.y] = 0.25f * asum;
            ushort2 vv = *(const ushort2*)(V + (size_t)ce.x * DIM + 2 * l);
            a0 += a * bf2f(vv.x);
            a1 += a * bf2f(vv.y);
        }
        if (active) {
            ushort2 o; o.x = f2bf(a0); o.y = f2bf(a1);
            *(ushort2*)(attended + (size_t)n * DIM + 2 * l) = o;
        }
    }
}

extern "C" void kernel_launch(void* const* d_in, const int* in_sizes, int n_in,
                              void* d_out, int out_size, void* d_ws, size_t ws_size,
                              hipStream_t stream)
{
    const float* x  = (const float*)d_in[0];
    const int* e32  = (const int*)d_in[1];
    const long long* e64 = (const long long*)d_in[1];
    const float* Wq = (const float*)d_in[2];
    const float* bq = (const float*)d_in[3];
    const float* Wk = (const float*)d_in[4];
    const float* bk = (const float*)d_in[5];
    const float* Wv = (const float*)d_in[6];
    const float* bv = (const float*)d_in[7];
    const float* Wo = (const float*)d_in[8];
    const float* bo = (const float*)d_in[9];

    int N = in_sizes[0] / DIM;
    int E = in_sizes[1] / 2;

    float* out = (float*)d_out;
    float* avg_out = out + (size_t)N * DIM;

    char* w = (char*)d_ws;
    auto carve = [&](size_t bytes) -> void* {
        void* p = (void*)w;
        w += (bytes + 255) & ~(size_t)255;
        return p;
    };
    unsigned short* Qb = (unsigned short*)carve((size_t)N * DIM * 2);  // reused as `attended`
    unsigned short* Kb = (unsigned short*)carve((size_t)N * DIM * 2);
    unsigned short* Vb = (unsigned short*)carve((size_t)N * DIM * 2);
    unsigned short* Wqb = (unsigned short*)carve(DIM * DIM * 2);
    unsigned short* Wkb = (unsigned short*)carve(DIM * DIM * 2);
    unsigned short* Wvb = (unsigned short*)carve(DIM * DIM * 2);
    unsigned short* Wob = (unsigned short*)carve(DIM * DIM * 2);
    int* deg    = (int*)carve((size_t)N * 4);
    int* tmp    = (int*)carve((size_t)N * 4);
    int* rowptr = (int*)carve(((size_t)N + 1) * 4);
    int* cursor = (int*)carve((size_t)N * 4);
    int* bsums  = (int*)carve(512 * 4);
    int* flag   = (int*)carve(256);
    int2* colEid = (int2*)carve((size_t)E * 8);

    hipMemsetAsync(deg, 0, (size_t)N * 4, stream);

    cast_w4<<<dim3(8, 4), 256, 0, stream>>>(Wq, Wk, Wv, Wo, Wqb, Wkb, Wvb, Wob);

    detect64<<<1, 256, 0, stream>>>(e32, flag, 2 * E);
    hist_kernel<<<(E + 255) / 256, 256, 0, stream>>>(e32, e64, flag, deg, E);
    int nb = (N + 1023) / 1024;
    scan1<<<nb, 256, 0, stream>>>(deg, tmp, bsums, N);
    scan2<<<1, 256, 0, stream>>>(bsums, nb);
    scan3c<<<(N + 255) / 256, 256, 0, stream>>>(tmp, bsums, deg, rowptr, cursor, N);
    scatter_kernel<<<(E + 255) / 256, 256, 0, stream>>>(e32, e64, flag, cursor, colEid, E);

    int gx = (N + 127) / 128;
    gemm_qkv_fused<<<gx, 256, 0, stream>>>(x, Wqb, Wkb, Wvb, bq, bk, bv, Qb, Kb, Vb, N);

    attn_kernel<<<(N + 3) / 4, 256, 0, stream>>>(Qb, Kb, Vb, rowptr, colEid,
                                                 Qb /*attended aliases Q*/, avg_out, N);

    gemm_final<<<gx, 256, 0, stream>>>(Qb, Wob, bo, x, out, N);
}